// Round 3
// baseline (889.239 us; speedup 1.0000x reference)
//
#include <hip/hip_runtime.h>
#include <hip/hip_bf16.h>
#include <stdint.h>

// Fused: C = GroupNorm(mish(hardtanh(x @ W^T + b_lin + b_ext))) * gw + gb
// x:[8192,4096] f32, W:[4096,4096] f32 (row-major, K-contig), out f32.
// Plan: fp32->bf16 convert into ws, then 128x128-tile bf16 MFMA GEMM with
// fully fused epilogue incl. GroupNorm (group width 128 == BN).

constexpr int Mdim = 8192;
constexpr int Ndim = 4096;
constexpr int Kdim = 4096;
constexpr int BM = 128, BN = 128, BK = 64;
constexpr float GN_EPS_F = 1e-5f;

typedef __bf16 bf16x8 __attribute__((ext_vector_type(8)));
typedef float f32x4 __attribute__((ext_vector_type(4)));

__device__ __forceinline__ unsigned short bf16_rne(float f) {
  unsigned int u = __float_as_uint(f);
  u += 0x7FFFu + ((u >> 16) & 1u);
  return (unsigned short)(u >> 16);
}

__global__ __launch_bounds__(256) void cvt_f32_bf16(const float* __restrict__ in,
                                                    unsigned short* __restrict__ out,
                                                    int n4) {
  int idx = blockIdx.x * blockDim.x + threadIdx.x;
  int stride = gridDim.x * blockDim.x;
  const float4* in4 = reinterpret_cast<const float4*>(in);
  ushort4* out4 = reinterpret_cast<ushort4*>(out);
  for (int i = idx; i < n4; i += stride) {
    float4 f = in4[i];
    ushort4 o;
    o.x = bf16_rne(f.x);
    o.y = bf16_rne(f.y);
    o.z = bf16_rne(f.z);
    o.w = bf16_rne(f.w);
    out4[i] = o;
  }
}

__device__ __forceinline__ void gload16(const void* g, void* l) {
  __builtin_amdgcn_global_load_lds((const __attribute__((address_space(1))) void*)g,
                                   (__attribute__((address_space(3))) void*)l,
                                   16, 0, 0);
}

// 128x128 tile, BK=64, 4 waves (2x2), 16x16x32 bf16 MFMA, 4x4 frags/wave.
// LDS staged in column-of-16B-chunk order: chunk (j, r) at byte (j*128+r)*16,
// j = k/8 (8 chunks per row of 64 bf16), r = tile row. Frag ds_read_b128 then
// hits 16 consecutive 16B slots per 16-lane phase -> conflict-free.
__global__ __launch_bounds__(256, 2) void fused_gemm_gn(
    const unsigned short* __restrict__ Abf,   // x bf16 [M][K]
    const unsigned short* __restrict__ Bbf,   // W bf16 [N][K]
    const float* __restrict__ blin,
    const float* __restrict__ bext,
    const float* __restrict__ gnw,
    const float* __restrict__ gnb,
    float* __restrict__ out) {
  __shared__ __align__(16) unsigned short As[BM * BK];
  __shared__ __align__(16) unsigned short Bs[BN * BK];
  __shared__ float red[2][BM][2];  // [col-wave][block row][sum, sumsq]

  // bijective XCD swizzle: nwg = 2048, divisible by 8
  int bid = blockIdx.x;
  int swz = (bid & 7) * 256 + (bid >> 3);
  int bx = swz & 31;   // N tile index (32)
  int by = swz >> 5;   // M tile index (64)
  int row0 = by * BM;
  int col0 = bx * BN;

  int tid = threadIdx.x;
  int w = tid >> 6;        // wave 0..3
  int lane = tid & 63;
  int wr = w >> 1;         // wave row (0/1) -> 64 M-rows
  int wc = w & 1;          // wave col (0/1) -> 64 N-cols
  int l4 = lane >> 4;      // 0..3
  int lm = lane & 15;      // 0..15

  // staging: 1024 chunks per tile; wave w, iter t handles chunks cbase..cbase+63
  int aoff[4], boff[4];
#pragma unroll
  for (int t = 0; t < 4; ++t) {
    int cbase = t * 256 + w * 64;
    int j = cbase >> 7;              // chunk column (k/8)
    int r = (cbase & 127) + lane;    // tile row for this lane
    aoff[t] = (row0 + r) * Kdim + j * 8;
    boff[t] = (col0 + r) * Kdim + j * 8;
  }

  f32x4 acc[4][4] = {};

  const bf16x8* Ap = reinterpret_cast<const bf16x8*>(As);
  const bf16x8* Bp = reinterpret_cast<const bf16x8*>(Bs);

  for (int kt = 0; kt < Kdim / BK; ++kt) {
    int kof = kt * BK;
#pragma unroll
    for (int t = 0; t < 4; ++t) {
      int cbase = t * 256 + w * 64;
      gload16(Abf + (aoff[t] + kof), (void*)&As[cbase * 8]);
      gload16(Bbf + (boff[t] + kof), (void*)&Bs[cbase * 8]);
    }
    __syncthreads();
#pragma unroll
    for (int kk = 0; kk < 2; ++kk) {
      bf16x8 a[4], b[4];
      int j = kk * 4 + l4;
#pragma unroll
      for (int mi = 0; mi < 4; ++mi)
        a[mi] = Ap[j * 128 + wr * 64 + mi * 16 + lm];
#pragma unroll
      for (int ni = 0; ni < 4; ++ni)
        b[ni] = Bp[j * 128 + wc * 64 + ni * 16 + lm];
#pragma unroll
      for (int mi = 0; mi < 4; ++mi)
#pragma unroll
        for (int ni = 0; ni < 4; ++ni)
          acc[mi][ni] = __builtin_amdgcn_mfma_f32_16x16x32_bf16(a[mi], b[ni], acc[mi][ni], 0, 0, 0);
    }
    __syncthreads();
  }

  // ---- epilogue: biases, hardtanh, mish, groupnorm (group width = BN = 128) ----
  float vbl[4], vbe[4], vgw[4], vgb[4];
#pragma unroll
  for (int ni = 0; ni < 4; ++ni) {
    int c = col0 + wc * 64 + ni * 16 + lm;
    vbl[ni] = blin[c];
    vbe[ni] = bext[c];
    vgw[ni] = gnw[c];
    vgb[ni] = gnb[c];
  }

  // activation + per-row partial sums; C/D layout: row=(lane>>4)*4+i, col=lane&15
#pragma unroll
  for (int mi = 0; mi < 4; ++mi) {
#pragma unroll
    for (int i = 0; i < 4; ++i) {
      float s1 = 0.f, s2 = 0.f;
#pragma unroll
      for (int ni = 0; ni < 4; ++ni) {
        float y = acc[mi][ni][i] + vbl[ni] + vbe[ni];
        y = fminf(fmaxf(y, -1.f), 1.f);
        // mish(y) = y * tanh(softplus(y)) = y*(t^2+2t)/(t^2+2t+2), t=e^y
        float t = __expf(y);
        float num = t * t + 2.f * t;
        float m = y * num / (num + 2.f);
        acc[mi][ni][i] = m;
        s1 += m;
        s2 += m * m;
      }
      // reduce across the 16-lane column group (same l4 => same row)
#pragma unroll
      for (int off = 1; off < 16; off <<= 1) {
        s1 += __shfl_xor(s1, off, 64);
        s2 += __shfl_xor(s2, off, 64);
      }
      if (lm == 0) {
        int r = wr * 64 + mi * 16 + l4 * 4 + i;
        red[wc][r][0] = s1;
        red[wc][r][1] = s2;
      }
    }
  }
  __syncthreads();

#pragma unroll
  for (int mi = 0; mi < 4; ++mi) {
#pragma unroll
    for (int i = 0; i < 4; ++i) {
      int r = wr * 64 + mi * 16 + l4 * 4 + i;
      float s1 = red[0][r][0] + red[1][r][0];
      float s2 = red[0][r][1] + red[1][r][1];
      float mean = s1 * (1.f / 128.f);
      float var = s2 * (1.f / 128.f) - mean * mean;
      float rstd = rsqrtf(var + GN_EPS_F);
      size_t rowg = (size_t)(row0 + r) * Ndim + col0 + wc * 64;
#pragma unroll
      for (int ni = 0; ni < 4; ++ni) {
        float v = (acc[mi][ni][i] - mean) * rstd * vgw[ni] + vgb[ni];
        out[rowg + ni * 16 + lm] = v;
      }
    }
  }
}

extern "C" void kernel_launch(void* const* d_in, const int* in_sizes, int n_in,
                              void* d_out, int out_size, void* d_ws, size_t ws_size,
                              hipStream_t stream) {
  const float* x   = (const float*)d_in[0];
  const float* wgt = (const float*)d_in[1];
  const float* bl  = (const float*)d_in[2];
  const float* be  = (const float*)d_in[3];
  const float* gw  = (const float*)d_in[4];
  const float* gb  = (const float*)d_in[5];
  float* out = (float*)d_out;

  unsigned short* xbf = (unsigned short*)d_ws;                       // 64 MiB
  unsigned short* wbf = xbf + (size_t)Mdim * Kdim;                   // +32 MiB

  cvt_f32_bf16<<<2048, 256, 0, stream>>>(x, xbf, Mdim * Kdim / 4);
  cvt_f32_bf16<<<2048, 256, 0, stream>>>(wgt, wbf, Ndim * Kdim / 4);

  int nwg = (Mdim / BM) * (Ndim / BN);  // 64*32 = 2048
  fused_gemm_gn<<<nwg, 256, 0, stream>>>(xbf, wbf, bl, be, gw, gb, out);
}

// Round 6
// 595.012 us; speedup vs baseline: 1.4945x; 1.4945x over previous
//
#include <hip/hip_runtime.h>
#include <hip/hip_bf16.h>
#include <stdint.h>

// Fused: C = GroupNorm(mish(hardtanh(x @ W^T + b_lin + b_ext))) * gw + gb
// x:[8192,4096] f32, W:[4096,4096] f32 (row-major, K-contig), out f32.
// fp32->bf16 convert into ws, then 128x128-tile bf16 MFMA GEMM with fused
// epilogue incl. GroupNorm (group width 128 == BN).
//
// R3 fix: staging is row-major chunks with XOR-swizzle (T2/rule#21):
//   chunk (r, j) of a [128 x 64bf16] tile lives at LDS slot r*8 + (j^(r&7)).
//   global_load_lds dest stays linear (base+lane*16); the per-lane GLOBAL
//   source applies the inverse permutation -> line-coalesced (1KB/instr).
//   ds_read_b128 applies the same XOR -> 2 lanes/bank (free).

constexpr int Mdim = 8192;
constexpr int Ndim = 4096;
constexpr int Kdim = 4096;
constexpr int BM = 128, BN = 128, BK = 64;
constexpr float GN_EPS_F = 1e-5f;

typedef __bf16 bf16x8 __attribute__((ext_vector_type(8)));
typedef float f32x4 __attribute__((ext_vector_type(4)));

__device__ __forceinline__ unsigned short bf16_rne(float f) {
  unsigned int u = __float_as_uint(f);
  u += 0x7FFFu + ((u >> 16) & 1u);
  return (unsigned short)(u >> 16);
}

// one kernel converts both arrays (x then W), grid-stride over float4s
__global__ __launch_bounds__(256) void cvt_both(const float* __restrict__ a,
                                                unsigned short* __restrict__ ao,
                                                int na4,
                                                const float* __restrict__ b,
                                                unsigned short* __restrict__ bo,
                                                int nb4) {
  int idx = blockIdx.x * blockDim.x + threadIdx.x;
  int stride = gridDim.x * blockDim.x;
  const float4* a4 = reinterpret_cast<const float4*>(a);
  const float4* b4 = reinterpret_cast<const float4*>(b);
  ushort4* ao4 = reinterpret_cast<ushort4*>(ao);
  ushort4* bo4 = reinterpret_cast<ushort4*>(bo);
  int total = na4 + nb4;
  for (int i = idx; i < total; i += stride) {
    const float4* src = (i < na4) ? &a4[i] : &b4[i - na4];
    ushort4* dst = (i < na4) ? &ao4[i] : &bo4[i - na4];
    float4 f = *src;
    ushort4 o;
    o.x = bf16_rne(f.x);
    o.y = bf16_rne(f.y);
    o.z = bf16_rne(f.z);
    o.w = bf16_rne(f.w);
    *dst = o;
  }
}

__device__ __forceinline__ void gload16(const void* g, void* l) {
  __builtin_amdgcn_global_load_lds((const __attribute__((address_space(1))) void*)g,
                                   (__attribute__((address_space(3))) void*)l,
                                   16, 0, 0);
}

__global__ __launch_bounds__(256, 2) void fused_gemm_gn(
    const unsigned short* __restrict__ Abf,   // x bf16 [M][K]
    const unsigned short* __restrict__ Bbf,   // W bf16 [N][K]
    const float* __restrict__ blin,
    const float* __restrict__ bext,
    const float* __restrict__ gnw,
    const float* __restrict__ gnb,
    float* __restrict__ out) {
  __shared__ __align__(16) unsigned short As[BM * BK];
  __shared__ __align__(16) unsigned short Bs[BN * BK];
  __shared__ float red[2][BM][2];  // [col-wave][block row][sum, sumsq]

  // bijective XCD swizzle: nwg = 2048, divisible by 8
  int bid = blockIdx.x;
  int swz = (bid & 7) * 256 + (bid >> 3);
  int bx = swz & 31;   // N tile index (32)
  int by = swz >> 5;   // M tile index (64)
  int row0 = by * BM;
  int col0 = bx * BN;

  int tid = threadIdx.x;
  int w = tid >> 6;        // wave 0..3
  int lane = tid & 63;
  int wr = w >> 1;         // wave row (0/1) -> 64 M-rows
  int wc = w & 1;          // wave col (0/1) -> 64 N-cols
  int l4 = lane >> 4;      // 0..3
  int lm = lane & 15;      // 0..15

  // staging: 1024 chunks per matrix; wave w, iter t handles LDS chunks
  // cbase..cbase+63 (linear dest). Lane l -> chunk c = cbase+l;
  // r = c>>3, j = (c&7) ^ (r&7)  (inverse of the read-side XOR).
  int aoff[4], boff[4];
#pragma unroll
  for (int t = 0; t < 4; ++t) {
    int cbase = t * 256 + w * 64;
    int c = cbase + lane;
    int r = c >> 3;
    int j = (c & 7) ^ (r & 7);
    aoff[t] = (row0 + r) * Kdim + j * 8;
    boff[t] = (col0 + r) * Kdim + j * 8;
  }

  f32x4 acc[4][4] = {};

  const bf16x8* Ap = reinterpret_cast<const bf16x8*>(As);
  const bf16x8* Bp = reinterpret_cast<const bf16x8*>(Bs);

  for (int kt = 0; kt < Kdim / BK; ++kt) {
    int kof = kt * BK;
#pragma unroll
    for (int t = 0; t < 4; ++t) {
      int cbase = t * 256 + w * 64;
      gload16(Abf + (aoff[t] + kof), (void*)&As[cbase * 8]);
      gload16(Bbf + (boff[t] + kof), (void*)&Bs[cbase * 8]);
    }
    __syncthreads();
#pragma unroll
    for (int kk = 0; kk < 2; ++kk) {
      bf16x8 a[4], b[4];
      int j = kk * 4 + l4;
      int jx = j ^ (lm & 7);   // swizzled slot within the row
#pragma unroll
      for (int mi = 0; mi < 4; ++mi)
        a[mi] = Ap[(wr * 64 + mi * 16 + lm) * 8 + jx];
#pragma unroll
      for (int ni = 0; ni < 4; ++ni)
        b[ni] = Bp[(wc * 64 + ni * 16 + lm) * 8 + jx];
#pragma unroll
      for (int mi = 0; mi < 4; ++mi)
#pragma unroll
        for (int ni = 0; ni < 4; ++ni)
          acc[mi][ni] = __builtin_amdgcn_mfma_f32_16x16x32_bf16(a[mi], b[ni], acc[mi][ni], 0, 0, 0);
    }
    __syncthreads();
  }

  // ---- epilogue: biases, hardtanh, mish, groupnorm (group width = BN = 128) ----
  float vbl[4], vbe[4], vgw[4], vgb[4];
#pragma unroll
  for (int ni = 0; ni < 4; ++ni) {
    int c = col0 + wc * 64 + ni * 16 + lm;
    vbl[ni] = blin[c];
    vbe[ni] = bext[c];
    vgw[ni] = gnw[c];
    vgb[ni] = gnb[c];
  }

  // activation + per-row partial sums; C/D layout: row=(lane>>4)*4+i, col=lane&15
#pragma unroll
  for (int mi = 0; mi < 4; ++mi) {
#pragma unroll
    for (int i = 0; i < 4; ++i) {
      float s1 = 0.f, s2 = 0.f;
#pragma unroll
      for (int ni = 0; ni < 4; ++ni) {
        float y = acc[mi][ni][i] + vbl[ni] + vbe[ni];
        y = fminf(fmaxf(y, -1.f), 1.f);
        // mish(y) = y * tanh(softplus(y)) = y*(t^2+2t)/(t^2+2t+2), t=e^y
        float t = __expf(y);
        float num = t * t + 2.f * t;
        float m = y * num / (num + 2.f);
        acc[mi][ni][i] = m;
        s1 += m;
        s2 += m * m;
      }
      // reduce across the 16-lane column group (same l4 => same row)
#pragma unroll
      for (int off = 1; off < 16; off <<= 1) {
        s1 += __shfl_xor(s1, off, 64);
        s2 += __shfl_xor(s2, off, 64);
      }
      if (lm == 0) {
        int r = wr * 64 + mi * 16 + l4 * 4 + i;
        red[wc][r][0] = s1;
        red[wc][r][1] = s2;
      }
    }
  }
  __syncthreads();

#pragma unroll
  for (int mi = 0; mi < 4; ++mi) {
#pragma unroll
    for (int i = 0; i < 4; ++i) {
      int r = wr * 64 + mi * 16 + l4 * 4 + i;
      float s1 = red[0][r][0] + red[1][r][0];
      float s2 = red[0][r][1] + red[1][r][1];
      float mean = s1 * (1.f / 128.f);
      float var = s2 * (1.f / 128.f) - mean * mean;
      float rstd = rsqrtf(var + GN_EPS_F);
      size_t rowg = (size_t)(row0 + r) * Ndim + col0 + wc * 64;
#pragma unroll
      for (int ni = 0; ni < 4; ++ni) {
        float v = (acc[mi][ni][i] - mean) * rstd * vgw[ni] + vgb[ni];
        out[rowg + ni * 16 + lm] = v;
      }
    }
  }
}

extern "C" void kernel_launch(void* const* d_in, const int* in_sizes, int n_in,
                              void* d_out, int out_size, void* d_ws, size_t ws_size,
                              hipStream_t stream) {
  const float* x   = (const float*)d_in[0];
  const float* wgt = (const float*)d_in[1];
  const float* bl  = (const float*)d_in[2];
  const float* be  = (const float*)d_in[3];
  const float* gw  = (const float*)d_in[4];
  const float* gb  = (const float*)d_in[5];
  float* out = (float*)d_out;

  unsigned short* xbf = (unsigned short*)d_ws;                       // 64 MiB
  unsigned short* wbf = xbf + (size_t)Mdim * Kdim;                   // +32 MiB

  cvt_both<<<2048, 256, 0, stream>>>(x, xbf, Mdim * Kdim / 4,
                                     wgt, wbf, Ndim * Kdim / 4);

  int nwg = (Mdim / BM) * (Ndim / BN);  // 64*32 = 2048
  fused_gemm_gn<<<nwg, 256, 0, stream>>>(xbf, wbf, bl, be, gw, gb, out);
}